// Round 12
// baseline (361.508 us; speedup 1.0000x reference)
//
#include <hip/hip_runtime.h>
#include <hip/hip_bf16.h>
#include <stdint.h>

#define NN 100000
#define NE 1600000
#define NBLK 256                 // edge-chunk blocks for hist/scatter
#define EPB (NE / NBLK)          // 6250 edges per block
#define NBINS 782                // ceil(NN/128) coarse bins of 128 nodes
#define NCELL (NBINS * NBLK)     // 200192 scan cells
#define NSB ((NCELL + 1023) / 1024)  // 196 scan blocks

// ---------------- bf16 helpers ----------------

__device__ __forceinline__ unsigned pack_bf16(float a, float b) {
    unsigned ua = __float_as_uint(a);
    unsigned ub = __float_as_uint(b);
    ua += 0x7FFFu + ((ua >> 16) & 1u);       // RNE
    ub += 0x7FFFu + ((ub >> 16) & 1u);
    return (ua >> 16) | (ub & 0xFFFF0000u);  // a -> low half (element 2k)
}
#define BF_LO(w) __uint_as_float((w) << 16)
#define BF_HI(w) __uint_as_float((w) & 0xFFFF0000u)

// ---------------- edge_index width detection (int32 vs int64) ----------------

__global__ void k_detect(const int* __restrict__ ei, int* __restrict__ flag) {
    if (threadIdx.x == 0) {
        int z = 0;
#pragma unroll
        for (int i = 0; i < 16; ++i) z |= ei[2 * i + 1];
        flag[0] = (z == 0) ? 1 : 0;
    }
}

// ---------------- CSR build via 2-level counting sort (NO global atomics) ----

__global__ void __launch_bounds__(256) k_hist(const int* __restrict__ ei,
                                              const int* __restrict__ flag,
                                              int* __restrict__ gcount) {
    __shared__ int lbin[NBINS];
    int t = threadIdx.x, blk = blockIdx.x;
    for (int i = t; i < NBINS; i += 256) lbin[i] = 0;
    __syncthreads();
    int is64 = flag[0];
    int e0 = blk * EPB;
    if (is64) {
        const int2* p = (const int2*)ei;
        for (int e = e0 + t; e < e0 + EPB; e += 256)
            atomicAdd(&lbin[p[NE + e].x >> 7], 1);
    } else {
        for (int e = e0 + t; e < e0 + EPB; e += 256)
            atomicAdd(&lbin[ei[NE + e] >> 7], 1);
    }
    __syncthreads();
    for (int b = t; b < NBINS; b += 256) gcount[b * NBLK + blk] = lbin[b];
}

__global__ void k_pscan1(const int* __restrict__ g, int* __restrict__ bsum) {
    __shared__ int sh[256];
    int t = threadIdx.x;
    int base = blockIdx.x * 1024 + t * 4;
    int s = 0;
#pragma unroll
    for (int j = 0; j < 4; ++j) { int i = base + j; if (i < NCELL) s += g[i]; }
    sh[t] = s; __syncthreads();
    for (int off = 128; off > 0; off >>= 1) {
        if (t < off) sh[t] += sh[t + off];
        __syncthreads();
    }
    if (t == 0) bsum[blockIdx.x] = sh[0];
}

__global__ void k_pscan2(const int* __restrict__ bsum, int* __restrict__ boff) {
    __shared__ int sh[256];
    int t = threadIdx.x;
    int v = (t < NSB) ? bsum[t] : 0;
    sh[t] = v; __syncthreads();
    for (int off = 1; off < 256; off <<= 1) {
        int tmp = (t >= off) ? sh[t - off] : 0;
        __syncthreads();
        sh[t] += tmp;
        __syncthreads();
    }
    if (t < NSB) boff[t] = sh[t] - v;
}

__global__ void k_pscan3(const int* __restrict__ g, const int* __restrict__ boff,
                         int* __restrict__ goff) {
    __shared__ int sh[256];
    int t = threadIdx.x;
    int base = blockIdx.x * 1024 + t * 4;
    int v[4]; int s = 0;
#pragma unroll
    for (int j = 0; j < 4; ++j) { int i = base + j; v[j] = (i < NCELL) ? g[i] : 0; s += v[j]; }
    sh[t] = s; __syncthreads();
    for (int off = 1; off < 256; off <<= 1) {
        int tmp = (t >= off) ? sh[t - off] : 0;
        __syncthreads();
        sh[t] += tmp;
        __syncthreads();
    }
    int run = sh[t] - s + boff[blockIdx.x];
#pragma unroll
    for (int j = 0; j < 4; ++j) {
        int i = base + j;
        if (i < NCELL) { goff[i] = run; run += v[j]; }
    }
}

// tmp entry: src (17 bits) | d_low7 << 17.
__global__ void __launch_bounds__(256) k_scatter(const int* __restrict__ ei,
                                                 const int* __restrict__ flag,
                                                 const int* __restrict__ goff,
                                                 unsigned* __restrict__ tmp) {
    __shared__ int lcur[NBINS];
    int t = threadIdx.x, blk = blockIdx.x;
    for (int i = t; i < NBINS; i += 256) lcur[i] = 0;
    __syncthreads();
    int is64 = flag[0];
    int e0 = blk * EPB;
    for (int e = e0 + t; e < e0 + EPB; e += 256) {
        int s, d;
        if (is64) {
            s = ((const int2*)ei)[e].x;
            d = ((const int2*)ei)[NE + e].x;
        } else {
            s = ei[e];
            d = ei[NE + e];
        }
        int b = d >> 7;
        int lr = atomicAdd(&lcur[b], 1);
        int pos = goff[b * NBLK + blk] + lr;
        tmp[pos] = (unsigned)s | ((unsigned)(d & 127) << 17);
    }
}

__global__ void __launch_bounds__(256) k_deg(const unsigned* __restrict__ tmp,
                                             const int* __restrict__ goff,
                                             int* __restrict__ rs,
                                             int* __restrict__ deg32,
                                             float* __restrict__ dinv) {
    __shared__ int hist[128];
    int b = blockIdx.x, t = threadIdx.x;
    if (t < 128) hist[t] = 0;
    __syncthreads();
    int bs = goff[b * NBLK];
    int be = (b == NBINS - 1) ? NE : goff[(b + 1) * NBLK];
    for (int e = bs + t; e < be; e += 256)
        atomicAdd(&hist[tmp[e] >> 17], 1);
    __syncthreads();
    if (t < 128) {
        int node = b * 128 + t;
        if (node < NN) {
            int c = hist[t];
            int loff = 0;
            for (int i = 0; i < t; ++i) loff += hist[i];
            rs[node] = bs + loff;
            deg32[node] = c;
            dinv[node] = rsqrtf((float)c + 1.0f);
        }
    }
    if (b == 0 && t == 0) rs[NN] = NE;
}

// csr entry: (src*8) | (deg<<21) — src*8 is the uint4-row base (128 B rows).
__global__ void __launch_bounds__(256) k_csr(const unsigned* __restrict__ tmp,
                                             const int* __restrict__ goff,
                                             const int* __restrict__ rs,
                                             const int* __restrict__ deg32,
                                             unsigned* __restrict__ csr) {
    __shared__ int cur[128];
    __shared__ int base_sh[128];
    int b = blockIdx.x, t = threadIdx.x;
    if (t < 128) {
        cur[t] = 0;
        int node = b * 128 + t;
        base_sh[t] = (node < NN) ? rs[node] : 0;
    }
    __syncthreads();
    int bs = goff[b * NBLK];
    int be = (b == NBINS - 1) ? NE : goff[(b + 1) * NBLK];
    for (int e = bs + t; e < be; e += 256) {
        unsigned v = tmp[e];
        int dl = v >> 17;
        unsigned s = v & 0x1FFFFu;
        int lr = atomicAdd(&cur[dl], 1);
        unsigned deg = (unsigned)min(deg32[s], 2047);
        csr[base_sh[dl] + lr] = (s << 3) | (deg << 21);
    }
}

// ---------------- fp32 GEMM -> bf16 H: H[N,64] = X[N,64] @ W[64,64] ----------
// lane = row; task = (64-row tile, 32-col half) -> acc[32] fits in VGPRs with
// NO spill (the R11 version's acc[64] spilled: VGPR_Count 56 < 64 live accs).

__global__ void __launch_bounds__(256) k_gemm(const float* __restrict__ X,
                                              const float* __restrict__ W,
                                              unsigned* __restrict__ Hb) {
    int task0 = (blockIdx.x * blockDim.x + threadIdx.x) >> 6;
    int nw = (gridDim.x * blockDim.x) >> 6;
    int lane = threadIdx.x & 63;
    const int ntasks = ((NN + 63) >> 6) * 2;    // 1563 tiles x 2 col-halves
    for (int task = task0; task < ntasks; task += nw) {
        int t = task >> 1;
        int ch = task & 1;                      // columns ch*32 .. ch*32+31
        int row = t * 64 + lane;
        int r = row < NN ? row : NN - 1;        // clamped lanes write duplicate data
        const float4* xp = (const float4*)(X + (size_t)r * 64);
        float acc[32];
#pragma unroll
        for (int c = 0; c < 32; ++c) acc[c] = 0.f;
#pragma unroll 4
        for (int k4 = 0; k4 < 16; ++k4) {
            float4 xv = xp[k4];
#pragma unroll
            for (int kj = 0; kj < 4; ++kj) {
                float xk = (kj == 0) ? xv.x : (kj == 1) ? xv.y : (kj == 2) ? xv.z : xv.w;
                const float4* wr = (const float4*)(W + (k4 * 4 + kj) * 64 + ch * 32);
#pragma unroll
                for (int c4 = 0; c4 < 8; ++c4) {
                    float4 wv = wr[c4];
                    acc[c4 * 4 + 0] += xk * wv.x;
                    acc[c4 * 4 + 1] += xk * wv.y;
                    acc[c4 * 4 + 2] += xk * wv.z;
                    acc[c4 * 4 + 3] += xk * wv.w;
                }
            }
        }
        // store 32 bf16 = 16 words = 4 uint4 at row base + half offset
        uint4* op = (uint4*)(Hb + (size_t)r * 32 + ch * 16);
#pragma unroll
        for (int q = 0; q < 4; ++q) {
            uint4 o;
            o.x = pack_bf16(acc[q * 8 + 0], acc[q * 8 + 1]);
            o.y = pack_bf16(acc[q * 8 + 2], acc[q * 8 + 3]);
            o.z = pack_bf16(acc[q * 8 + 4], acc[q * 8 + 5]);
            o.w = pack_bf16(acc[q * 8 + 6], acc[q * 8 + 7]);
            op[q] = o;
        }
    }
}

// ---------------- aggregation: one wave per node, 8 groups x 8 lanes x uint4,
// software-pipelined csr prefetch; 16 x 128B row-gathers in flight ------------

#define EDGE_ACC(p, r)                                                        \
    {                                                                         \
        float w = rsqrtf((float)((p) >> 21) + 1.0f);                          \
        a0 += BF_LO((r).x) * w; a1 += BF_HI((r).x) * w;                       \
        a2 += BF_LO((r).y) * w; a3 += BF_HI((r).y) * w;                       \
        a4 += BF_LO((r).z) * w; a5 += BF_HI((r).z) * w;                       \
        a6 += BF_LO((r).w) * w; a7 += BF_HI((r).w) * w;                       \
    }

__global__ void __launch_bounds__(256) k_agg(const uint4* __restrict__ hb,
                                             const int* __restrict__ rs,
                                             const unsigned* __restrict__ csr,
                                             const float* __restrict__ dinv,
                                             const float* __restrict__ bias,
                                             float4* __restrict__ out4) {
    int wid = (blockIdx.x * blockDim.x + threadIdx.x) >> 6;
    int lane = threadIdx.x & 63;
    int node = __builtin_amdgcn_readfirstlane(wid);
    if (node >= NN) return;
    int g = lane >> 3;        // edge-stream group 0..7
    int s = lane & 7;         // feature octet 0..7
    float dn = dinv[node];
    int e0 = rs[node], e1 = rs[node + 1];
    float a0 = 0.f, a1 = 0.f, a2 = 0.f, a3 = 0.f;
    float a4 = 0.f, a5 = 0.f, a6 = 0.f, a7 = 0.f;
    int e = e0 + g;
    unsigned p0 = csr[e];
    unsigned p1 = csr[e + 8];
    for (; e + 8 < e1; e += 16) {
        unsigned q0 = csr[e + 16];
        unsigned q1 = csr[e + 24];
        uint4 r0 = hb[(p0 & 0x1FFFFFu) + s];
        uint4 r1 = hb[(p1 & 0x1FFFFFu) + s];
        EDGE_ACC(p0, r0);
        EDGE_ACC(p1, r1);
        p0 = q0; p1 = q1;
    }
    if (e < e1) {
        uint4 r0 = hb[(p0 & 0x1FFFFFu) + s];
        EDGE_ACC(p0, r0);
    }
#pragma unroll
    for (int m = 8; m <= 32; m <<= 1) {
        a0 += __shfl_xor(a0, m); a1 += __shfl_xor(a1, m);
        a2 += __shfl_xor(a2, m); a3 += __shfl_xor(a3, m);
        a4 += __shfl_xor(a4, m); a5 += __shfl_xor(a5, m);
        a6 += __shfl_xor(a6, m); a7 += __shfl_xor(a7, m);
    }
    if (lane < 8) {
        uint4 r = hb[(size_t)node * 8 + s];    // self row, features s*8..s*8+7
        const float4* bp = (const float4*)(bias + s * 8);
        float4 b0 = bp[0], b1v = bp[1];
        float4 o0, o1;
        o0.x = fmaxf((a0 + BF_LO(r.x) * dn) * dn + b0.x, 0.f);
        o0.y = fmaxf((a1 + BF_HI(r.x) * dn) * dn + b0.y, 0.f);
        o0.z = fmaxf((a2 + BF_LO(r.y) * dn) * dn + b0.z, 0.f);
        o0.w = fmaxf((a3 + BF_HI(r.y) * dn) * dn + b0.w, 0.f);
        o1.x = fmaxf((a4 + BF_LO(r.z) * dn) * dn + b1v.x, 0.f);
        o1.y = fmaxf((a5 + BF_HI(r.z) * dn) * dn + b1v.y, 0.f);
        o1.z = fmaxf((a6 + BF_LO(r.w) * dn) * dn + b1v.z, 0.f);
        o1.w = fmaxf((a7 + BF_HI(r.w) * dn) * dn + b1v.w, 0.f);
        out4[(size_t)node * 16 + s * 2] = o0;
        out4[(size_t)node * 16 + s * 2 + 1] = o1;
    }
}

// ---------------- launch ----------------

extern "C" void kernel_launch(void* const* d_in, const int* in_sizes, int n_in,
                              void* d_out, int out_size, void* d_ws, size_t ws_size,
                              hipStream_t stream) {
    const float* x  = (const float*)d_in[0];            // [NN,64] fp32
    const int* ei   = (const int*)d_in[1];              // [2,NE] int32/int64 (detected)
    const float* W1 = (const float*)d_in[2];
    const float* b1 = (const float*)d_in[3];
    const float* W2 = (const float*)d_in[4];
    const float* b2 = (const float*)d_in[5];

    char* ws = (char*)d_ws;
    size_t off = 0;
    auto alloc = [&](size_t bytes) -> char* {
        char* p = ws + off;
        off = (off + bytes + 511) & ~(size_t)511;
        return p;
    };
    int*      flag  = (int*)alloc(64);
    int*      gcount= (int*)alloc((size_t)NCELL * 4);    // 800 KB
    int*      goff  = (int*)alloc((size_t)NCELL * 4);    // 800 KB
    int*      bsum  = (int*)alloc((size_t)NSB * 4);
    int*      boff  = (int*)alloc((size_t)NSB * 4);
    unsigned* tmp   = (unsigned*)alloc((size_t)NE * 4);  // 6.4 MB
    unsigned* csr   = (unsigned*)alloc((size_t)NE * 4);  // 6.4 MB
    int*      rs    = (int*)alloc((size_t)(NN + 1) * 4);
    int*      deg32 = (int*)alloc((size_t)NN * 4);
    float*    dinv  = (float*)alloc((size_t)NN * 4);
    unsigned* hbuf  = (unsigned*)alloc((size_t)NN * 32 * 4);  // 12.8 MB bf16 h (128 B rows)
    float*    hmid  = (float*)d_out;                     // layer-1 fp32 act (reuse d_out)

    k_detect<<<1, 64, 0, stream>>>(ei, flag);
    k_hist<<<NBLK, 256, 0, stream>>>(ei, flag, gcount);
    k_pscan1<<<NSB, 256, 0, stream>>>(gcount, bsum);
    k_pscan2<<<1, 256, 0, stream>>>(bsum, boff);
    k_pscan3<<<NSB, 256, 0, stream>>>(gcount, boff, goff);
    k_scatter<<<NBLK, 256, 0, stream>>>(ei, flag, goff, tmp);
    k_deg<<<NBINS, 256, 0, stream>>>(tmp, goff, rs, deg32, dinv);
    k_csr<<<NBINS, 256, 0, stream>>>(tmp, goff, rs, deg32, csr);

    // layer 1: hbuf(bf16) = x @ W1 ; hmid(=d_out, fp32) = relu(agg(hbuf) + b1)
    k_gemm<<<782, 256, 0, stream>>>(x, W1, hbuf);
    k_agg<<<(NN * 64) / 256, 256, 0, stream>>>((const uint4*)hbuf, rs, csr, dinv, b1,
                                               (float4*)hmid);
    // layer 2: hbuf(bf16) = hmid @ W2 ; d_out = relu(agg(hbuf) + b2)
    k_gemm<<<782, 256, 0, stream>>>(hmid, W2, hbuf);
    k_agg<<<(NN * 64) / 256, 256, 0, stream>>>((const uint4*)hbuf, rs, csr, dinv, b2,
                                               (float4*)d_out);
}

// Round 13
// 270.860 us; speedup vs baseline: 1.3347x; 1.3347x over previous
//
#include <hip/hip_runtime.h>
#include <hip/hip_bf16.h>
#include <stdint.h>

#define NN 100000
#define NE 1600000
#define NBLK 256                 // edge-chunk blocks for hist/scatter
#define EPB (NE / NBLK)          // 6250 edges per block
#define NBINS 782                // ceil(NN/128) coarse bins of 128 nodes
#define NCELL (NBINS * NBLK)     // 200192 scan cells
#define NSB ((NCELL + 1023) / 1024)  // 196 scan blocks

// ---------------- bf16 helpers ----------------

__device__ __forceinline__ unsigned pack_bf16(float a, float b) {
    unsigned ua = __float_as_uint(a);
    unsigned ub = __float_as_uint(b);
    ua += 0x7FFFu + ((ua >> 16) & 1u);       // RNE
    ub += 0x7FFFu + ((ub >> 16) & 1u);
    return (ua >> 16) | (ub & 0xFFFF0000u);  // a -> low half (element 2k)
}
#define BF_LO(w) __uint_as_float((w) << 16)
#define BF_HI(w) __uint_as_float((w) & 0xFFFF0000u)

// ---------------- edge_index width detection (int32 vs int64) ----------------

__global__ void k_detect(const int* __restrict__ ei, int* __restrict__ flag) {
    if (threadIdx.x == 0) {
        int z = 0;
#pragma unroll
        for (int i = 0; i < 16; ++i) z |= ei[2 * i + 1];
        flag[0] = (z == 0) ? 1 : 0;
    }
}

// ---------------- CSR build via 2-level counting sort (NO global atomics) ----

__global__ void __launch_bounds__(256) k_hist(const int* __restrict__ ei,
                                              const int* __restrict__ flag,
                                              int* __restrict__ gcount) {
    __shared__ int lbin[NBINS];
    int t = threadIdx.x, blk = blockIdx.x;
    for (int i = t; i < NBINS; i += 256) lbin[i] = 0;
    __syncthreads();
    int is64 = flag[0];
    int e0 = blk * EPB;
    if (is64) {
        const int2* p = (const int2*)ei;
        for (int e = e0 + t; e < e0 + EPB; e += 256)
            atomicAdd(&lbin[p[NE + e].x >> 7], 1);
    } else {
        for (int e = e0 + t; e < e0 + EPB; e += 256)
            atomicAdd(&lbin[ei[NE + e] >> 7], 1);
    }
    __syncthreads();
    for (int b = t; b < NBINS; b += 256) gcount[b * NBLK + blk] = lbin[b];
}

__global__ void k_pscan1(const int* __restrict__ g, int* __restrict__ bsum) {
    __shared__ int sh[256];
    int t = threadIdx.x;
    int base = blockIdx.x * 1024 + t * 4;
    int s = 0;
#pragma unroll
    for (int j = 0; j < 4; ++j) { int i = base + j; if (i < NCELL) s += g[i]; }
    sh[t] = s; __syncthreads();
    for (int off = 128; off > 0; off >>= 1) {
        if (t < off) sh[t] += sh[t + off];
        __syncthreads();
    }
    if (t == 0) bsum[blockIdx.x] = sh[0];
}

__global__ void k_pscan2(const int* __restrict__ bsum, int* __restrict__ boff) {
    __shared__ int sh[256];
    int t = threadIdx.x;
    int v = (t < NSB) ? bsum[t] : 0;
    sh[t] = v; __syncthreads();
    for (int off = 1; off < 256; off <<= 1) {
        int tmp = (t >= off) ? sh[t - off] : 0;
        __syncthreads();
        sh[t] += tmp;
        __syncthreads();
    }
    if (t < NSB) boff[t] = sh[t] - v;
}

__global__ void k_pscan3(const int* __restrict__ g, const int* __restrict__ boff,
                         int* __restrict__ goff) {
    __shared__ int sh[256];
    int t = threadIdx.x;
    int base = blockIdx.x * 1024 + t * 4;
    int v[4]; int s = 0;
#pragma unroll
    for (int j = 0; j < 4; ++j) { int i = base + j; v[j] = (i < NCELL) ? g[i] : 0; s += v[j]; }
    sh[t] = s; __syncthreads();
    for (int off = 1; off < 256; off <<= 1) {
        int tmp = (t >= off) ? sh[t - off] : 0;
        __syncthreads();
        sh[t] += tmp;
        __syncthreads();
    }
    int run = sh[t] - s + boff[blockIdx.x];
#pragma unroll
    for (int j = 0; j < 4; ++j) {
        int i = base + j;
        if (i < NCELL) { goff[i] = run; run += v[j]; }
    }
}

// tmp entry: src (17 bits) | d_low7 << 17.
__global__ void __launch_bounds__(256) k_scatter(const int* __restrict__ ei,
                                                 const int* __restrict__ flag,
                                                 const int* __restrict__ goff,
                                                 unsigned* __restrict__ tmp) {
    __shared__ int lcur[NBINS];
    int t = threadIdx.x, blk = blockIdx.x;
    for (int i = t; i < NBINS; i += 256) lcur[i] = 0;
    __syncthreads();
    int is64 = flag[0];
    int e0 = blk * EPB;
    for (int e = e0 + t; e < e0 + EPB; e += 256) {
        int s, d;
        if (is64) {
            s = ((const int2*)ei)[e].x;
            d = ((const int2*)ei)[NE + e].x;
        } else {
            s = ei[e];
            d = ei[NE + e];
        }
        int b = d >> 7;
        int lr = atomicAdd(&lcur[b], 1);
        int pos = goff[b * NBLK + blk] + lr;
        tmp[pos] = (unsigned)s | ((unsigned)(d & 127) << 17);
    }
}

__global__ void __launch_bounds__(256) k_deg(const unsigned* __restrict__ tmp,
                                             const int* __restrict__ goff,
                                             int* __restrict__ rs,
                                             int* __restrict__ deg32,
                                             float* __restrict__ dinv) {
    __shared__ int hist[128];
    int b = blockIdx.x, t = threadIdx.x;
    if (t < 128) hist[t] = 0;
    __syncthreads();
    int bs = goff[b * NBLK];
    int be = (b == NBINS - 1) ? NE : goff[(b + 1) * NBLK];
    for (int e = bs + t; e < be; e += 256)
        atomicAdd(&hist[tmp[e] >> 17], 1);
    __syncthreads();
    if (t < 128) {
        int node = b * 128 + t;
        if (node < NN) {
            int c = hist[t];
            int loff = 0;
            for (int i = 0; i < t; ++i) loff += hist[i];
            rs[node] = bs + loff;
            deg32[node] = c;
            dinv[node] = rsqrtf((float)c + 1.0f);
        }
    }
    if (b == 0 && t == 0) rs[NN] = NE;
}

// csr entry: (src*8) | (deg<<21) — src*8 is the uint4-row base (128 B rows).
__global__ void __launch_bounds__(256) k_csr(const unsigned* __restrict__ tmp,
                                             const int* __restrict__ goff,
                                             const int* __restrict__ rs,
                                             const int* __restrict__ deg32,
                                             unsigned* __restrict__ csr) {
    __shared__ int cur[128];
    __shared__ int base_sh[128];
    int b = blockIdx.x, t = threadIdx.x;
    if (t < 128) {
        cur[t] = 0;
        int node = b * 128 + t;
        base_sh[t] = (node < NN) ? rs[node] : 0;
    }
    __syncthreads();
    int bs = goff[b * NBLK];
    int be = (b == NBINS - 1) ? NE : goff[(b + 1) * NBLK];
    for (int e = bs + t; e < be; e += 256) {
        unsigned v = tmp[e];
        int dl = v >> 17;
        unsigned s = v & 0x1FFFFu;
        int lr = atomicAdd(&cur[dl], 1);
        unsigned deg = (unsigned)min(deg32[s], 2047);
        csr[base_sh[dl] + lr] = (s << 3) | (deg << 21);
    }
}

// ---------------- fp32 GEMM -> bf16 H: H[N,64] = X[N,64] @ W[64,64] ----------
// One task per wave: task = (64-row tile, 32-col half), acc[32] (no spill).
// task forced wave-uniform via readfirstlane so the W address is provably
// scalar -> compiler emits s_load for W (R12's ch*32 made it a 64-lane
// broadcast vector load: SGPR_Count fell 112->32 and dur rose 51->77 us).

__global__ void __launch_bounds__(256) k_gemm(const float* __restrict__ X,
                                              const float* __restrict__ W,
                                              unsigned* __restrict__ Hb) {
    int wid = (blockIdx.x * 256 + threadIdx.x) >> 6;
    int lane = threadIdx.x & 63;
    int task = __builtin_amdgcn_readfirstlane(wid);
    const int ntasks = ((NN + 63) >> 6) * 2;    // 1563 tiles x 2 col-halves = 3126
    if (task >= ntasks) return;
    int t = task >> 1;
    int ch = task & 1;                          // columns ch*32 .. ch*32+31 (scalar)
    int row = t * 64 + lane;
    int r = row < NN ? row : NN - 1;            // clamped lanes write duplicate data
    const float4* xp = (const float4*)(X + (size_t)r * 64);
    const float* Wb = W + ch * 32;              // scalar base
    float acc[32];
#pragma unroll
    for (int c = 0; c < 32; ++c) acc[c] = 0.f;
#pragma unroll 4
    for (int k4 = 0; k4 < 16; ++k4) {
        float4 xv = xp[k4];
#pragma unroll
        for (int kj = 0; kj < 4; ++kj) {
            float xk = (kj == 0) ? xv.x : (kj == 1) ? xv.y : (kj == 2) ? xv.z : xv.w;
            const float4* wr = (const float4*)(Wb + (k4 * 4 + kj) * 64);
#pragma unroll
            for (int c4 = 0; c4 < 8; ++c4) {
                float4 wv = wr[c4];
                acc[c4 * 4 + 0] += xk * wv.x;
                acc[c4 * 4 + 1] += xk * wv.y;
                acc[c4 * 4 + 2] += xk * wv.z;
                acc[c4 * 4 + 3] += xk * wv.w;
            }
        }
    }
    // store 32 bf16 = 16 words = 4 uint4 at row base + half offset
    uint4* op = (uint4*)(Hb + (size_t)r * 32 + ch * 16);
#pragma unroll
    for (int q = 0; q < 4; ++q) {
        uint4 o;
        o.x = pack_bf16(acc[q * 8 + 0], acc[q * 8 + 1]);
        o.y = pack_bf16(acc[q * 8 + 2], acc[q * 8 + 3]);
        o.z = pack_bf16(acc[q * 8 + 4], acc[q * 8 + 5]);
        o.w = pack_bf16(acc[q * 8 + 6], acc[q * 8 + 7]);
        op[q] = o;
    }
}

// ---------------- aggregation: one wave per node, 8 groups x 8 lanes x uint4,
// software-pipelined csr prefetch; 16 x 128B row-gathers in flight ------------

#define EDGE_ACC(p, r)                                                        \
    {                                                                         \
        float w = rsqrtf((float)((p) >> 21) + 1.0f);                          \
        a0 += BF_LO((r).x) * w; a1 += BF_HI((r).x) * w;                       \
        a2 += BF_LO((r).y) * w; a3 += BF_HI((r).y) * w;                       \
        a4 += BF_LO((r).z) * w; a5 += BF_HI((r).z) * w;                       \
        a6 += BF_LO((r).w) * w; a7 += BF_HI((r).w) * w;                       \
    }

__global__ void __launch_bounds__(256) k_agg(const uint4* __restrict__ hb,
                                             const int* __restrict__ rs,
                                             const unsigned* __restrict__ csr,
                                             const float* __restrict__ dinv,
                                             const float* __restrict__ bias,
                                             float4* __restrict__ out4) {
    int wid = (blockIdx.x * blockDim.x + threadIdx.x) >> 6;
    int lane = threadIdx.x & 63;
    int node = __builtin_amdgcn_readfirstlane(wid);
    if (node >= NN) return;
    int g = lane >> 3;        // edge-stream group 0..7
    int s = lane & 7;         // feature octet 0..7
    float dn = dinv[node];
    int e0 = rs[node], e1 = rs[node + 1];
    float a0 = 0.f, a1 = 0.f, a2 = 0.f, a3 = 0.f;
    float a4 = 0.f, a5 = 0.f, a6 = 0.f, a7 = 0.f;
    int e = e0 + g;
    unsigned p0 = csr[e];
    unsigned p1 = csr[e + 8];
    for (; e + 8 < e1; e += 16) {
        unsigned q0 = csr[e + 16];
        unsigned q1 = csr[e + 24];
        uint4 r0 = hb[(p0 & 0x1FFFFFu) + s];
        uint4 r1 = hb[(p1 & 0x1FFFFFu) + s];
        EDGE_ACC(p0, r0);
        EDGE_ACC(p1, r1);
        p0 = q0; p1 = q1;
    }
    if (e < e1) {
        uint4 r0 = hb[(p0 & 0x1FFFFFu) + s];
        EDGE_ACC(p0, r0);
    }
#pragma unroll
    for (int m = 8; m <= 32; m <<= 1) {
        a0 += __shfl_xor(a0, m); a1 += __shfl_xor(a1, m);
        a2 += __shfl_xor(a2, m); a3 += __shfl_xor(a3, m);
        a4 += __shfl_xor(a4, m); a5 += __shfl_xor(a5, m);
        a6 += __shfl_xor(a6, m); a7 += __shfl_xor(a7, m);
    }
    if (lane < 8) {
        uint4 r = hb[(size_t)node * 8 + s];    // self row, features s*8..s*8+7
        const float4* bp = (const float4*)(bias + s * 8);
        float4 b0 = bp[0], b1v = bp[1];
        float4 o0, o1;
        o0.x = fmaxf((a0 + BF_LO(r.x) * dn) * dn + b0.x, 0.f);
        o0.y = fmaxf((a1 + BF_HI(r.x) * dn) * dn + b0.y, 0.f);
        o0.z = fmaxf((a2 + BF_LO(r.y) * dn) * dn + b0.z, 0.f);
        o0.w = fmaxf((a3 + BF_HI(r.y) * dn) * dn + b0.w, 0.f);
        o1.x = fmaxf((a4 + BF_LO(r.z) * dn) * dn + b1v.x, 0.f);
        o1.y = fmaxf((a5 + BF_HI(r.z) * dn) * dn + b1v.y, 0.f);
        o1.z = fmaxf((a6 + BF_LO(r.w) * dn) * dn + b1v.z, 0.f);
        o1.w = fmaxf((a7 + BF_HI(r.w) * dn) * dn + b1v.w, 0.f);
        out4[(size_t)node * 16 + s * 2] = o0;
        out4[(size_t)node * 16 + s * 2 + 1] = o1;
    }
}

// ---------------- launch ----------------

extern "C" void kernel_launch(void* const* d_in, const int* in_sizes, int n_in,
                              void* d_out, int out_size, void* d_ws, size_t ws_size,
                              hipStream_t stream) {
    const float* x  = (const float*)d_in[0];            // [NN,64] fp32
    const int* ei   = (const int*)d_in[1];              // [2,NE] int32/int64 (detected)
    const float* W1 = (const float*)d_in[2];
    const float* b1 = (const float*)d_in[3];
    const float* W2 = (const float*)d_in[4];
    const float* b2 = (const float*)d_in[5];

    char* ws = (char*)d_ws;
    size_t off = 0;
    auto alloc = [&](size_t bytes) -> char* {
        char* p = ws + off;
        off = (off + bytes + 511) & ~(size_t)511;
        return p;
    };
    int*      flag  = (int*)alloc(64);
    int*      gcount= (int*)alloc((size_t)NCELL * 4);    // 800 KB
    int*      goff  = (int*)alloc((size_t)NCELL * 4);    // 800 KB
    int*      bsum  = (int*)alloc((size_t)NSB * 4);
    int*      boff  = (int*)alloc((size_t)NSB * 4);
    unsigned* tmp   = (unsigned*)alloc((size_t)NE * 4);  // 6.4 MB
    unsigned* csr   = (unsigned*)alloc((size_t)NE * 4);  // 6.4 MB
    int*      rs    = (int*)alloc((size_t)(NN + 1) * 4);
    int*      deg32 = (int*)alloc((size_t)NN * 4);
    float*    dinv  = (float*)alloc((size_t)NN * 4);
    unsigned* hbuf  = (unsigned*)alloc((size_t)NN * 32 * 4);  // 12.8 MB bf16 h (128 B rows)
    float*    hmid  = (float*)d_out;                     // layer-1 fp32 act (reuse d_out)

    k_detect<<<1, 64, 0, stream>>>(ei, flag);
    k_hist<<<NBLK, 256, 0, stream>>>(ei, flag, gcount);
    k_pscan1<<<NSB, 256, 0, stream>>>(gcount, bsum);
    k_pscan2<<<1, 256, 0, stream>>>(bsum, boff);
    k_pscan3<<<NSB, 256, 0, stream>>>(gcount, boff, goff);
    k_scatter<<<NBLK, 256, 0, stream>>>(ei, flag, goff, tmp);
    k_deg<<<NBINS, 256, 0, stream>>>(tmp, goff, rs, deg32, dinv);
    k_csr<<<NBINS, 256, 0, stream>>>(tmp, goff, rs, deg32, csr);

    // layer 1: hbuf(bf16) = x @ W1 ; hmid(=d_out, fp32) = relu(agg(hbuf) + b1)
    k_gemm<<<782, 256, 0, stream>>>(x, W1, hbuf);
    k_agg<<<(NN * 64) / 256, 256, 0, stream>>>((const uint4*)hbuf, rs, csr, dinv, b1,
                                               (float4*)hmid);
    // layer 2: hbuf(bf16) = hmid @ W2 ; d_out = relu(agg(hbuf) + b2)
    k_gemm<<<782, 256, 0, stream>>>(hmid, W2, hbuf);
    k_agg<<<(NN * 64) / 256, 256, 0, stream>>>((const uint4*)hbuf, rs, csr, dinv, b2,
                                               (float4*)d_out);
}